// Round 12
// baseline (125.907 us; speedup 1.0000x reference)
//
#include <hip/hip_runtime.h>
#include <stdint.h>

// f32 I/O. Two-phase: pre_cast builds bf16 X, bf16 X^T, f32 |x|^2 in d_ws once;
// gauss_main: staged 2-phase fused kernel. Fallback to r11 kernel if ws too small.
// R1: 8 waves = 4 bands x 2 S-halves. R2: batch-affine XCD swizzle.
// R5: coalesced LDS staging. R6/7: waves_per_eu(4,4) (no spill) + swapped GEMM1
//     + cvt_pk P-writes. R9/R10: XOR swizzle on xs/xst PROVEN (64.1us gauss).
// R8/R8b/R11 lessons: three multi-change restructures (P-swizzle x2, 16-wave
//     S-quarter split) failed correctness despite lane-trace verification.
//     Policy: consolidate on the proven R10 structure; only provably-safe edits.
// R12: (a) fuse each P write pair into ONE uint2 b64 store (8B-aligned by
//     construction: row*280=0 mod 8, col*2=0 mod 8; identical bytes) — halves
//     P-write LDS instruction count, the dominant remaining 4-way-conflict
//     source (even-dword parity: 64 lanes -> 16 even banks).
//     (b) hoist the 4 sq norm loads above GEMM1 into the prefetch cluster so
//     their latency hides under GEMM1 MFMAs (pure code motion).
#define T_DIM 2048
#define C_DIM 64
#define BT 128
#define BS 128
#define NTILE (T_DIM / BS)
#define PSP 140  // sm_p stride (els), proven R7 layout
#define PS 136   // r11 fallback stride

// swizzled element index: row-major power-of-2 stride, 16B-chunk XOR (row&7)
#define XS_IDX(row, chunk) (((row) << 6) + ((((chunk) ^ ((row) & 7)) << 3)))
#define XT_IDX(row, chunk) (((row) << 7) + ((((chunk) ^ ((row) & 7)) << 3)))

typedef __bf16 bf16x8v __attribute__((ext_vector_type(8)));
typedef float f32x4 __attribute__((ext_vector_type(4)));

#if defined(__has_builtin)
#if __has_builtin(__builtin_amdgcn_exp2f)
#define EXP2F(x) __builtin_amdgcn_exp2f(x)
#else
#define EXP2F(x) exp2f(x)
#endif
#else
#define EXP2F(x) exp2f(x)
#endif

__device__ __forceinline__ unsigned short f32_to_bf16_rne(float f) {
  union { float f; unsigned int x; } v; v.f = f;
  unsigned int u = v.x;
  u += 0x7fffu + ((u >> 16) & 1u);
  return (unsigned short)(u >> 16);
}
__device__ __forceinline__ uint4 pack8(const unsigned short* v) {
  uint4 u;
  u.x = (unsigned)v[0] | ((unsigned)v[1] << 16);
  u.y = (unsigned)v[2] | ((unsigned)v[3] << 16);
  u.z = (unsigned)v[4] | ((unsigned)v[5] << 16);
  u.w = (unsigned)v[6] | ((unsigned)v[7] << 16);
  return u;
}
// packed f32x2 -> bf16x2 (RNE), one instruction
__device__ __forceinline__ unsigned cvt_pk_bf16(float lo, float hi) {
  unsigned r;
  asm("v_cvt_pk_bf16_f32 %0, %1, %2" : "=v"(r) : "v"(lo), "v"(hi));
  return r;
}

// ---------------- pre-pass: f32 -> bf16 X, bf16 X^T, f32 row norms ----------------
__global__ __launch_bounds__(256, 4)
void pre_cast(const float* __restrict__ x, unsigned short* __restrict__ xbf,
              unsigned short* __restrict__ xtbf, float* __restrict__ sq) {
  __shared__ __align__(16) unsigned short tile[64 * 68];
  int bx = blockIdx.x, by = blockIdx.y;
  int b, t0i;
  if (gridDim.x == 32 && gridDim.y == 32) {
    const int c = bx & 7;
    const int r = (by << 2) | (bx >> 3);   // 0..127
    b = (c << 2) + (r >> 5);
    t0i = r & 31;
  } else { b = by; t0i = bx; }
  const int t0 = t0i * 64;
  const int tid = threadIdx.x;
  const int r = tid >> 2, q = tid & 3;

  const float* src = x + ((size_t)b * T_DIM + t0 + r) * C_DIM + q * 16;
  float part = 0.f;
  unsigned short vals[16];
#pragma unroll
  for (int i = 0; i < 4; ++i) {
    f32x4 v = *(const f32x4*)(src + 4 * i);
#pragma unroll
    for (int j = 0; j < 4; ++j) { part += v[j] * v[j]; vals[4 * i + j] = f32_to_bf16_rne(v[j]); }
  }
  part += __shfl_xor(part, 1);
  part += __shfl_xor(part, 2);
  if (q == 0) sq[(size_t)b * T_DIM + t0 + r] = part;

  uint4 p0 = pack8(vals), p1 = pack8(vals + 8);
  unsigned short* dst = xbf + ((size_t)b * T_DIM + t0 + r) * C_DIM + q * 16;
  *(uint4*)dst = p0;
  *(uint4*)(dst + 8) = p1;
  *(uint4*)(&tile[r * 68 + q * 16]) = p0;
  *(uint4*)(&tile[r * 68 + q * 16 + 8]) = p1;
  __syncthreads();

  const int cc = tid >> 2, tq = tid & 3;  // 4 consecutive lanes share cc -> 128B coalesced stores
  unsigned short tv[16];
#pragma unroll
  for (int j = 0; j < 16; ++j) tv[j] = tile[(tq * 16 + j) * 68 + cc];
  unsigned short* dT = xtbf + ((size_t)b * C_DIM + cc) * T_DIM + t0 + tq * 16;
  *(uint4*)dT = pack8(tv);
  *(uint4*)(dT + 8) = pack8(tv + 8);
}

// ---------------- main: staged 2-phase fused kernel ----------------
// HW-verified 16x16x32 bf16 MFMA layouts (m89/m91/m97/m120):
//   A: A[m=lane&15][k=(lane>>4)*8+j]; B: lane reads row n of B^T, k-contig
//   C/D: col=lane&15 (= B's n), row=(lane>>4)*4+reg (= A's m)
__global__ __attribute__((amdgpu_flat_work_group_size(512, 512), amdgpu_waves_per_eu(4, 4)))
void gauss_main(const float* __restrict__ x, const unsigned short* __restrict__ xbf,
                const unsigned short* __restrict__ xtbf, const float* __restrict__ sqn,
                const float* __restrict__ rs, float* __restrict__ out) {
  __shared__ __align__(16) unsigned short sm_xs[BS * 64];      // Xs tile  [s][c], swz (16KB)
  __shared__ __align__(16) unsigned short sm_xst[C_DIM * 128]; // Xs^T tile [c][s], swz (16KB)
  __shared__ __align__(16) unsigned short sm_p[BT * PSP];      // P bf16 [t][s], R7 layout (35KB)

  // batch-affine XCD swizzle: XCD c handles batches 4c..4c+3 (2MB < 4MB L2).
  int bx = blockIdx.x, by = blockIdx.y;
  int b, t0i;
  if (gridDim.x == 16 && gridDim.y == 32) {
    const int c = bx & 7;
    const int r = (by << 1) | (bx >> 3);   // 0..63
    b = (c << 2) + (r >> 4);
    t0i = r & 15;
  } else { b = by; t0i = bx; }
  const int t0 = t0i * BT;

  const int tid = threadIdx.x;
  const int w = tid >> 6, lane = tid & 63, l15 = lane & 15, quad = lane >> 4;
  const int wq = w & 3, sw = w >> 2;     // band index, S-half index
  const int trow = wq * 32;              // this wave's 32-row band
  const int scol = sw * 64;              // this wave's 64-col S half within each 128 tile
  const int sch = sw * 8;                // chunk offset of the S half (64 els = 8 chunks)

  // staging indices: coalesced 32B/thread from xb rows and xtb rows (chunk units)
  const int xr = tid >> 2, xch = (tid & 3) * 2;  // xs:  row 0..127, chunks {0,2,4,6}
  const int tr = tid >> 3, tch = (tid & 7) * 2;  // xst: row 0..63,  chunks {0..14}

  float sigma = rs[0];
  if (!(sigma == sigma) || !(sigma >= 0.f) || sigma > 1e3f) sigma = 0.01f;
  const float c1 = sigma * 1.4426950408889634f, c2 = 2.0f * c1;

  const unsigned short* xb  = xbf  + (size_t)b * T_DIM * C_DIM;
  const unsigned short* xtb = xtbf + (size_t)b * C_DIM * T_DIM;
  const float* sqb = sqn + (size_t)b * T_DIM;

  // Q B-frags (b128 from bf16 X; one-time strided read, off the hot loop)
  bf16x8v qf[2][2];
#pragma unroll
  for (int mt = 0; mt < 2; ++mt)
#pragma unroll
    for (int kk = 0; kk < 2; ++kk)
      qf[mt][kk] = *(const bf16x8v*)(xb + (size_t)(t0 + trow + mt * 16 + l15) * C_DIM + kk * 32 + quad * 8);

  // per-lane t-norm: t = trow + mt*16 + l15 (swapped-GEMM1 P layout)
  float sTrL[2];
#pragma unroll
  for (int mt = 0; mt < 2; ++mt)
    sTrL[mt] = c1 * sqb[t0 + trow + mt * 16 + l15];

  f32x4 oacc[2][4];
#pragma unroll
  for (int mt = 0; mt < 2; ++mt)
#pragma unroll
    for (int nt = 0; nt < 4; ++nt)
#pragma unroll
      for (int r = 0; r < 4; ++r) oacc[mt][nt][r] = 0.f;

  // prologue: load tile 0 into staging regs (single bank)
  uint4 a0, a1, b0, b1;
  a0 = *(const uint4*)(xb + (size_t)xr * C_DIM + xch * 8);
  a1 = *(const uint4*)(xb + (size_t)xr * C_DIM + xch * 8 + 8);
  b0 = *(const uint4*)(xtb + (size_t)tr * T_DIM + tch * 8);
  b1 = *(const uint4*)(xtb + (size_t)tr * T_DIM + tch * 8 + 8);

#pragma unroll 1
  for (int it = 0; it < NTILE; ++it) {
    const int s0 = it * BS;
    // stage tile it into LDS (swizzled destinations, chunk-granular)
    *(uint4*)&sm_xs[XS_IDX(xr, xch)]      = a0;
    *(uint4*)&sm_xs[XS_IDX(xr, xch + 1)]  = a1;
    *(uint4*)&sm_xst[XT_IDX(tr, tch)]     = b0;
    *(uint4*)&sm_xst[XT_IDX(tr, tch + 1)] = b1;
    __syncthreads();

    // issue next-tile loads into the same regs (pinned live before the
    // closing barrier; HBM/L2 latency hides under the compute below)
    const int sn = ((it + 1) & (NTILE - 1)) * BS;
    a0 = *(const uint4*)(xb + (size_t)(sn + xr) * C_DIM + xch * 8);
    a1 = *(const uint4*)(xb + (size_t)(sn + xr) * C_DIM + xch * 8 + 8);
    b0 = *(const uint4*)(xtb + (size_t)tr * T_DIM + sn + tch * 8);
    b1 = *(const uint4*)(xtb + (size_t)tr * T_DIM + sn + tch * 8 + 8);

    // hoisted s-norm loads: issue with the prefetch cluster; latency hides
    // under GEMM1's MFMAs (consumed only in the exp pass below)
    f32x4 sq4v[4];
#pragma unroll
    for (int nt = 0; nt < 4; ++nt)
      sq4v[nt] = *(const f32x4*)(sqb + s0 + scol + nt * 16 + quad * 4);

    // GEMM1 (swapped): A = Xs-frag (m=s), B = Q-frag (n=t)
    // -> pacc[mt][nt][reg] = inner[t=trow+mt*16+l15][s=scol+nt*16+quad*4+reg]
    f32x4 pacc[2][4];
#pragma unroll
    for (int mt = 0; mt < 2; ++mt)
#pragma unroll
      for (int nt = 0; nt < 4; ++nt)
#pragma unroll
        for (int r = 0; r < 4; ++r) pacc[mt][nt][r] = 0.f;
#pragma unroll
    for (int nt = 0; nt < 4; ++nt) {
      const int srow = scol + nt * 16 + l15;
#pragma unroll
      for (int kk = 0; kk < 2; ++kk) {
        bf16x8v xfr = *(const bf16x8v*)&sm_xs[XS_IDX(srow, kk * 4 + quad)];
        pacc[0][nt] = __builtin_amdgcn_mfma_f32_16x16x32_bf16(xfr, qf[0][kk], pacc[0][nt], 0, 0, 0);
        pacc[1][nt] = __builtin_amdgcn_mfma_f32_16x16x32_bf16(xfr, qf[1][kk], pacc[1][nt], 0, 0, 0);
      }
    }

    // exp pass: lane-local s pairs -> cvt_pk -> ONE b64 P write per (nt,mt)
    // (8B-aligned by construction: row*280 % 8 == 0, col*2 % 8 == 0; bytes
    // identical to the former b32 pair)
#pragma unroll
    for (int nt = 0; nt < 4; ++nt) {
      float cs0 = c1 * sq4v[nt][0], cs1 = c1 * sq4v[nt][1];
      float cs2 = c1 * sq4v[nt][2], cs3 = c1 * sq4v[nt][3];
#pragma unroll
      for (int mt = 0; mt < 2; ++mt) {
        unsigned short* prow = sm_p + (trow + mt * 16 + l15) * PSP + scol + nt * 16 + quad * 4;
        float g0 = c2 * pacc[mt][nt][0] - (sTrL[mt] + cs0);
        float g1 = c2 * pacc[mt][nt][1] - (sTrL[mt] + cs1);
        float g2 = c2 * pacc[mt][nt][2] - (sTrL[mt] + cs2);
        float g3 = c2 * pacc[mt][nt][3] - (sTrL[mt] + cs3);
        g0 = (g0 < 0.f) ? g0 : 0.f;
        g1 = (g1 < 0.f) ? g1 : 0.f;
        g2 = (g2 < 0.f) ? g2 : 0.f;
        g3 = (g3 < 0.f) ? g3 : 0.f;
        uint2 pk;
        pk.x = cvt_pk_bf16(EXP2F(g0), EXP2F(g1));
        pk.y = cvt_pk_bf16(EXP2F(g2), EXP2F(g3));
        *(uint2*)prow = pk;
      }
    }
    // no __syncthreads: each wave reads back only its own rows x col-half

    // GEMM2: O += P * Xs; A from sm_p (R7 layout), B from xst LDS (swizzled)
#pragma unroll
    for (int kk = 0; kk < 2; ++kk) {
      bf16x8v af[2];
#pragma unroll
      for (int mt = 0; mt < 2; ++mt)
        af[mt] = *(const bf16x8v*)(sm_p + (trow + mt * 16 + l15) * PSP + scol + kk * 32 + quad * 8);
#pragma unroll
      for (int nt = 0; nt < 4; ++nt) {
        bf16x8v bfr = *(const bf16x8v*)&sm_xst[XT_IDX(nt * 16 + l15, sch + kk * 4 + quad)];
        oacc[0][nt] = __builtin_amdgcn_mfma_f32_16x16x32_bf16(af[0], bfr, oacc[0][nt], 0, 0, 0);
        oacc[1][nt] = __builtin_amdgcn_mfma_f32_16x16x32_bf16(af[1], bfr, oacc[1][nt], 0, 0, 0);
      }
    }

    // pin next-tile loads live here (prevents sinking past the barrier)
    asm volatile("" :: "v"(a0.x), "v"(a0.y), "v"(a0.z), "v"(a0.w),
                       "v"(a1.x), "v"(a1.y), "v"(a1.z), "v"(a1.w),
                       "v"(b0.x), "v"(b0.y), "v"(b0.z), "v"(b0.w),
                       "v"(b1.x), "v"(b1.y), "v"(b1.z), "v"(b1.w));
    __syncthreads();
  }

  // combine the two S-half partial accumulators (waves w and w+4), then epilogue
  // (R7 proven: stride 33, 256x33x4 = 33792 B <= 35840 B sm_p)
  __syncthreads();
  float* scr = (float*)sm_p;
  if (sw == 1) {
#pragma unroll
    for (int mt = 0; mt < 2; ++mt)
#pragma unroll
      for (int nt = 0; nt < 4; ++nt)
#pragma unroll
        for (int reg = 0; reg < 4; ++reg)
          scr[(wq * 64 + lane) * 33 + (mt * 4 + nt) * 4 + reg] = oacc[mt][nt][reg];
  }
  __syncthreads();
  if (sw == 0) {
#pragma unroll
    for (int mt = 0; mt < 2; ++mt) {
#pragma unroll
      for (int nt = 0; nt < 4; ++nt) {
#pragma unroll
        for (int reg = 0; reg < 4; ++reg) {
          int row = trow + mt * 16 + quad * 4 + reg;
          int col = nt * 16 + l15;
          size_t idx = (size_t)((size_t)b * T_DIM + t0 + row) * C_DIM + col;
          float part = scr[(wq * 64 + lane) * 33 + (mt * 4 + nt) * 4 + reg];
          out[idx] = x[idx] + oacc[mt][nt][reg] + part;
        }
      }
    }
  }
}

// ---------------- fallback: proven r11 kernel (ws too small) ----------------
__global__ __launch_bounds__(256, 2)
void gauss_attn_f32(const float* __restrict__ x, const float* __restrict__ rs,
                    float* __restrict__ out) {
  __shared__ __align__(16) unsigned short sm_xst[C_DIM * PS];
  __shared__ __align__(16) unsigned short sm_p[BT * PS];
  __shared__ float sm_sT[BT];
  __shared__ float sm_sS[BS];
  __shared__ float sm_part[2 * BS];

  const int b = blockIdx.y, t0 = blockIdx.x * BT, tid = threadIdx.x;
  const int w = tid >> 6, lane = tid & 63, l15 = lane & 15, quad = lane >> 4;

  float sigma = rs[0];
  if (!(sigma == sigma) || !(sigma >= 0.f) || sigma > 1e3f) sigma = 0.01f;
  const float c1 = sigma * 1.4426950408889634f, c2 = 2.0f * c1;
  const float* xb = x + (size_t)b * T_DIM * C_DIM;

  if (tid < BT) {
    const f32x4* r4 = (const f32x4*)(xb + (size_t)(t0 + tid) * C_DIM);
    float s = 0.f;
#pragma unroll
    for (int i = 0; i < 16; ++i) { f32x4 v = r4[i]; s += v[0]*v[0] + v[1]*v[1] + v[2]*v[2] + v[3]*v[3]; }
    sm_sT[tid] = s;
  }
  bf16x8v qf[2][2];
#pragma unroll
  for (int mt = 0; mt < 2; ++mt) {
    const float* qp = xb + (size_t)(t0 + w * 32 + mt * 16 + l15) * C_DIM + quad * 8;
#pragma unroll
    for (int kk = 0; kk < 2; ++kk) {
      f32x4 a0 = *(const f32x4*)(qp + kk * 32);
      f32x4 a1 = *(const f32x4*)(qp + kk * 32 + 4);
      union { unsigned short u[8]; bf16x8v v; } pk;
#pragma unroll
      for (int j = 0; j < 4; ++j) { pk.u[j] = f32_to_bf16_rne(a0[j]); pk.u[4+j] = f32_to_bf16_rne(a1[j]); }
      qf[mt][kk] = pk.v;
    }
  }
  __syncthreads();
  float sTr[2][4];
#pragma unroll
  for (int mt = 0; mt < 2; ++mt)
#pragma unroll
    for (int reg = 0; reg < 4; ++reg) sTr[mt][reg] = c1 * sm_sT[w * 32 + mt * 16 + quad * 4 + reg];
  f32x4 oacc[2][4];
#pragma unroll
  for (int mt = 0; mt < 2; ++mt)
#pragma unroll
    for (int nt = 0; nt < 4; ++nt)
#pragma unroll
      for (int r = 0; r < 4; ++r) oacc[mt][nt][r] = 0.f;
  const int sidx = tid & 127, h = tid >> 7;
  for (int it = 0; it < T_DIM / BS; ++it) {
    const int s0 = it * BS;
    __syncthreads();
    {
      float part = 0.f;
      const float* sp = xb + (size_t)(s0 + sidx) * C_DIM + h * 32;
#pragma unroll
      for (int r = 0; r < 8; ++r) {
        f32x4 v = *(const f32x4*)(sp + r * 4);
        part += v[0]*v[0] + v[1]*v[1] + v[2]*v[2] + v[3]*v[3];
        const int c0 = h * 32 + r * 4;
        sm_xst[(c0+0)*PS+sidx] = f32_to_bf16_rne(v[0]);
        sm_xst[(c0+1)*PS+sidx] = f32_to_bf16_rne(v[1]);
        sm_xst[(c0+2)*PS+sidx] = f32_to_bf16_rne(v[2]);
        sm_xst[(c0+3)*PS+sidx] = f32_to_bf16_rne(v[3]);
      }
      sm_part[h * BS + sidx] = part;
    }
    __syncthreads();
    if (tid < BS) sm_sS[tid] = sm_part[tid] + sm_part[BS + tid];
    __syncthreads();
    f32x4 pacc[2][8];
#pragma unroll
    for (int mt = 0; mt < 2; ++mt)
#pragma unroll
      for (int nt = 0; nt < 8; ++nt)
#pragma unroll
        for (int r = 0; r < 4; ++r) pacc[mt][nt][r] = 0.f;
#pragma unroll
    for (int nt = 0; nt < 8; ++nt) {
      const float* bp = xb + (size_t)(s0 + nt * 16 + l15) * C_DIM + quad * 8;
#pragma unroll
      for (int kk = 0; kk < 2; ++kk) {
        f32x4 b0 = *(const f32x4*)(bp + kk * 32);
        f32x4 b1 = *(const f32x4*)(bp + kk * 32 + 4);
        union { unsigned short u[8]; bf16x8v v; } pk;
#pragma unroll
        for (int j = 0; j < 4; ++j) { pk.u[j] = f32_to_bf16_rne(b0[j]); pk.u[4+j] = f32_to_bf16_rne(b1[j]); }
        pacc[0][nt] = __builtin_amdgcn_mfma_f32_16x16x32_bf16(qf[0][kk], pk.v, pacc[0][nt], 0, 0, 0);
        pacc[1][nt] = __builtin_amdgcn_mfma_f32_16x16x32_bf16(qf[1][kk], pk.v, pacc[1][nt], 0, 0, 0);
      }
    }
#pragma unroll
    for (int nt = 0; nt < 8; ++nt) {
      const float sSv = c1 * sm_sS[nt * 16 + l15];
#pragma unroll
      for (int mt = 0; mt < 2; ++mt)
#pragma unroll
        for (int reg = 0; reg < 4; ++reg) {
          float arg = c2 * pacc[mt][nt][reg] - (sTr[mt][reg] + sSv);
          arg = (arg < 0.f) ? arg : 0.f;
          sm_p[(w*32+mt*16+quad*4+reg)*PS + nt*16+l15] = f32_to_bf16_rne(EXP2F(arg));
        }
    }
    __syncthreads();
#pragma unroll
    for (int kk = 0; kk < 4; ++kk) {
      bf16x8v af[2];
#pragma unroll
      for (int mt = 0; mt < 2; ++mt)
        af[mt] = *(const bf16x8v*)(sm_p + (w*32+mt*16+l15)*PS + kk*32 + quad*8);
#pragma unroll
      for (int nt = 0; nt < 4; ++nt) {
        bf16x8v bfr = *(const bf16x8v*)(sm_xst + (nt*16+l15)*PS + kk*32 + quad*8);
        oacc[0][nt] = __builtin_amdgcn_mfma_f32_16x16x32_bf16(af[0], bfr, oacc[0][nt], 0, 0, 0);
        oacc[1][nt] = __builtin_amdgcn_mfma_f32_16x16x32_bf16(af[1], bfr, oacc[1][nt], 0, 0, 0);
      }
    }
  }
#pragma unroll
  for (int mt = 0; mt < 2; ++mt)
#pragma unroll
    for (int nt = 0; nt < 4; ++nt)
#pragma unroll
      for (int reg = 0; reg < 4; ++reg) {
        int row = w * 32 + mt * 16 + quad * 4 + reg;
        int col = nt * 16 + l15;
        size_t idx = (size_t)((size_t)b * T_DIM + t0 + row) * C_DIM + col;
        out[idx] = x[idx] + oacc[mt][nt][reg];
      }
}

extern "C" void kernel_launch(void* const* d_in, const int* in_sizes, int n_in,
                              void* d_out, int out_size, void* d_ws, size_t ws_size,
                              hipStream_t stream) {
  const float* x  = (const float*)d_in[0];
  const float* rs = (const float*)d_in[1];
  float* outp = (float*)d_out;
  int B = in_sizes[0] / (T_DIM * C_DIM);
  if (B < 1) B = 1;
  size_t xel = (size_t)B * T_DIM * C_DIM;
  size_t need = xel * 2 * 2 + (size_t)B * T_DIM * 4;
  if (ws_size >= need) {
    unsigned short* xbf  = (unsigned short*)d_ws;
    unsigned short* xtbf = xbf + xel;
    float* sq = (float*)(xtbf + xel);
    pre_cast<<<dim3(T_DIM / 64, B), 256, 0, stream>>>(x, xbf, xtbf, sq);
    gauss_main<<<dim3(T_DIM / BT, B), 512, 0, stream>>>(x, xbf, xtbf, sq, rs, outp);
  } else {
    gauss_attn_f32<<<dim3(T_DIM / BT, B), 256, 0, stream>>>(x, rs, outp);
  }
}

// Round 14
// 125.378 us; speedup vs baseline: 1.0042x; 1.0042x over previous
//
#include <hip/hip_runtime.h>
#include <stdint.h>

// f32 I/O. Two-phase: pre_cast builds bf16 X, bf16 X^T, f32 |x|^2 in d_ws once;
// gauss_main: staged 2-phase fused kernel. Fallback to r11 kernel if ws too small.
// R1: 8 waves = 4 bands x 2 S-halves. R2: batch-affine XCD swizzle.
// R5: coalesced LDS staging. R6/7: waves_per_eu(4,4) (no spill) + swapped GEMM1
//     + cvt_pk P-writes. R9/R10: XOR swizzle on xs/xst PROVEN (64.1us gauss).
// R12: fused b64 P-writes + hoisted sq loads (conflicts 5.2e6->3.1e6,
//     gauss 60.7us, total 125.9us) — BEST VERIFIED STATE.
// R8/R8b/R11/R13 lessons: four structural changes (P-swizzle x2, 16-wave
//     S-quarter split, sm_p/sm_xs lifetime alias) failed correctness at
//     absmax ~100-300 despite passing static lane-trace/ordering verification.
//     The remaining latency-bound headroom (MfmaUtil 22%, VALU 40%, occ 34%)
//     requires exactly that class of change; under this workflow its expected
//     value is negative. Final state = R12 verbatim.
#define T_DIM 2048
#define C_DIM 64
#define BT 128
#define BS 128
#define NTILE (T_DIM / BS)
#define PSP 140  // sm_p stride (els), proven R7 layout
#define PS 136   // r11 fallback stride

// swizzled element index: row-major power-of-2 stride, 16B-chunk XOR (row&7)
#define XS_IDX(row, chunk) (((row) << 6) + ((((chunk) ^ ((row) & 7)) << 3)))
#define XT_IDX(row, chunk) (((row) << 7) + ((((chunk) ^ ((row) & 7)) << 3)))

typedef __bf16 bf16x8v __attribute__((ext_vector_type(8)));
typedef float f32x4 __attribute__((ext_vector_type(4)));

#if defined(__has_builtin)
#if __has_builtin(__builtin_amdgcn_exp2f)
#define EXP2F(x) __builtin_amdgcn_exp2f(x)
#else
#define EXP2F(x) exp2f(x)
#endif
#else
#define EXP2F(x) exp2f(x)
#endif

__device__ __forceinline__ unsigned short f32_to_bf16_rne(float f) {
  union { float f; unsigned int x; } v; v.f = f;
  unsigned int u = v.x;
  u += 0x7fffu + ((u >> 16) & 1u);
  return (unsigned short)(u >> 16);
}
__device__ __forceinline__ uint4 pack8(const unsigned short* v) {
  uint4 u;
  u.x = (unsigned)v[0] | ((unsigned)v[1] << 16);
  u.y = (unsigned)v[2] | ((unsigned)v[3] << 16);
  u.z = (unsigned)v[4] | ((unsigned)v[5] << 16);
  u.w = (unsigned)v[6] | ((unsigned)v[7] << 16);
  return u;
}
// packed f32x2 -> bf16x2 (RNE), one instruction
__device__ __forceinline__ unsigned cvt_pk_bf16(float lo, float hi) {
  unsigned r;
  asm("v_cvt_pk_bf16_f32 %0, %1, %2" : "=v"(r) : "v"(lo), "v"(hi));
  return r;
}

// ---------------- pre-pass: f32 -> bf16 X, bf16 X^T, f32 row norms ----------------
__global__ __launch_bounds__(256, 4)
void pre_cast(const float* __restrict__ x, unsigned short* __restrict__ xbf,
              unsigned short* __restrict__ xtbf, float* __restrict__ sq) {
  __shared__ __align__(16) unsigned short tile[64 * 68];
  int bx = blockIdx.x, by = blockIdx.y;
  int b, t0i;
  if (gridDim.x == 32 && gridDim.y == 32) {
    const int c = bx & 7;
    const int r = (by << 2) | (bx >> 3);   // 0..127
    b = (c << 2) + (r >> 5);
    t0i = r & 31;
  } else { b = by; t0i = bx; }
  const int t0 = t0i * 64;
  const int tid = threadIdx.x;
  const int r = tid >> 2, q = tid & 3;

  const float* src = x + ((size_t)b * T_DIM + t0 + r) * C_DIM + q * 16;
  float part = 0.f;
  unsigned short vals[16];
#pragma unroll
  for (int i = 0; i < 4; ++i) {
    f32x4 v = *(const f32x4*)(src + 4 * i);
#pragma unroll
    for (int j = 0; j < 4; ++j) { part += v[j] * v[j]; vals[4 * i + j] = f32_to_bf16_rne(v[j]); }
  }
  part += __shfl_xor(part, 1);
  part += __shfl_xor(part, 2);
  if (q == 0) sq[(size_t)b * T_DIM + t0 + r] = part;

  uint4 p0 = pack8(vals), p1 = pack8(vals + 8);
  unsigned short* dst = xbf + ((size_t)b * T_DIM + t0 + r) * C_DIM + q * 16;
  *(uint4*)dst = p0;
  *(uint4*)(dst + 8) = p1;
  *(uint4*)(&tile[r * 68 + q * 16]) = p0;
  *(uint4*)(&tile[r * 68 + q * 16 + 8]) = p1;
  __syncthreads();

  const int cc = tid >> 2, tq = tid & 3;  // 4 consecutive lanes share cc -> 128B coalesced stores
  unsigned short tv[16];
#pragma unroll
  for (int j = 0; j < 16; ++j) tv[j] = tile[(tq * 16 + j) * 68 + cc];
  unsigned short* dT = xtbf + ((size_t)b * C_DIM + cc) * T_DIM + t0 + tq * 16;
  *(uint4*)dT = pack8(tv);
  *(uint4*)(dT + 8) = pack8(tv + 8);
}

// ---------------- main: staged 2-phase fused kernel ----------------
// HW-verified 16x16x32 bf16 MFMA layouts (m89/m91/m97/m120):
//   A: A[m=lane&15][k=(lane>>4)*8+j]; B: lane reads row n of B^T, k-contig
//   C/D: col=lane&15 (= B's n), row=(lane>>4)*4+reg (= A's m)
__global__ __attribute__((amdgpu_flat_work_group_size(512, 512), amdgpu_waves_per_eu(4, 4)))
void gauss_main(const float* __restrict__ x, const unsigned short* __restrict__ xbf,
                const unsigned short* __restrict__ xtbf, const float* __restrict__ sqn,
                const float* __restrict__ rs, float* __restrict__ out) {
  __shared__ __align__(16) unsigned short sm_xs[BS * 64];      // Xs tile  [s][c], swz (16KB)
  __shared__ __align__(16) unsigned short sm_xst[C_DIM * 128]; // Xs^T tile [c][s], swz (16KB)
  __shared__ __align__(16) unsigned short sm_p[BT * PSP];      // P bf16 [t][s], R7 layout (35KB)

  // batch-affine XCD swizzle: XCD c handles batches 4c..4c+3 (2MB < 4MB L2).
  int bx = blockIdx.x, by = blockIdx.y;
  int b, t0i;
  if (gridDim.x == 16 && gridDim.y == 32) {
    const int c = bx & 7;
    const int r = (by << 1) | (bx >> 3);   // 0..63
    b = (c << 2) + (r >> 4);
    t0i = r & 15;
  } else { b = by; t0i = bx; }
  const int t0 = t0i * BT;

  const int tid = threadIdx.x;
  const int w = tid >> 6, lane = tid & 63, l15 = lane & 15, quad = lane >> 4;
  const int wq = w & 3, sw = w >> 2;     // band index, S-half index
  const int trow = wq * 32;              // this wave's 32-row band
  const int scol = sw * 64;              // this wave's 64-col S half within each 128 tile
  const int sch = sw * 8;                // chunk offset of the S half (64 els = 8 chunks)

  // staging indices: coalesced 32B/thread from xb rows and xtb rows (chunk units)
  const int xr = tid >> 2, xch = (tid & 3) * 2;  // xs:  row 0..127, chunks {0,2,4,6}
  const int tr = tid >> 3, tch = (tid & 7) * 2;  // xst: row 0..63,  chunks {0..14}

  float sigma = rs[0];
  if (!(sigma == sigma) || !(sigma >= 0.f) || sigma > 1e3f) sigma = 0.01f;
  const float c1 = sigma * 1.4426950408889634f, c2 = 2.0f * c1;

  const unsigned short* xb  = xbf  + (size_t)b * T_DIM * C_DIM;
  const unsigned short* xtb = xtbf + (size_t)b * C_DIM * T_DIM;
  const float* sqb = sqn + (size_t)b * T_DIM;

  // Q B-frags (b128 from bf16 X; one-time strided read, off the hot loop)
  bf16x8v qf[2][2];
#pragma unroll
  for (int mt = 0; mt < 2; ++mt)
#pragma unroll
    for (int kk = 0; kk < 2; ++kk)
      qf[mt][kk] = *(const bf16x8v*)(xb + (size_t)(t0 + trow + mt * 16 + l15) * C_DIM + kk * 32 + quad * 8);

  // per-lane t-norm: t = trow + mt*16 + l15 (swapped-GEMM1 P layout)
  float sTrL[2];
#pragma unroll
  for (int mt = 0; mt < 2; ++mt)
    sTrL[mt] = c1 * sqb[t0 + trow + mt * 16 + l15];

  f32x4 oacc[2][4];
#pragma unroll
  for (int mt = 0; mt < 2; ++mt)
#pragma unroll
    for (int nt = 0; nt < 4; ++nt)
#pragma unroll
      for (int r = 0; r < 4; ++r) oacc[mt][nt][r] = 0.f;

  // prologue: load tile 0 into staging regs (single bank)
  uint4 a0, a1, b0, b1;
  a0 = *(const uint4*)(xb + (size_t)xr * C_DIM + xch * 8);
  a1 = *(const uint4*)(xb + (size_t)xr * C_DIM + xch * 8 + 8);
  b0 = *(const uint4*)(xtb + (size_t)tr * T_DIM + tch * 8);
  b1 = *(const uint4*)(xtb + (size_t)tr * T_DIM + tch * 8 + 8);

#pragma unroll 1
  for (int it = 0; it < NTILE; ++it) {
    const int s0 = it * BS;
    // stage tile it into LDS (swizzled destinations, chunk-granular)
    *(uint4*)&sm_xs[XS_IDX(xr, xch)]      = a0;
    *(uint4*)&sm_xs[XS_IDX(xr, xch + 1)]  = a1;
    *(uint4*)&sm_xst[XT_IDX(tr, tch)]     = b0;
    *(uint4*)&sm_xst[XT_IDX(tr, tch + 1)] = b1;
    __syncthreads();

    // issue next-tile loads into the same regs (pinned live before the
    // closing barrier; HBM/L2 latency hides under the compute below)
    const int sn = ((it + 1) & (NTILE - 1)) * BS;
    a0 = *(const uint4*)(xb + (size_t)(sn + xr) * C_DIM + xch * 8);
    a1 = *(const uint4*)(xb + (size_t)(sn + xr) * C_DIM + xch * 8 + 8);
    b0 = *(const uint4*)(xtb + (size_t)tr * T_DIM + sn + tch * 8);
    b1 = *(const uint4*)(xtb + (size_t)tr * T_DIM + sn + tch * 8 + 8);

    // hoisted s-norm loads: issue with the prefetch cluster; latency hides
    // under GEMM1's MFMAs (consumed only in the exp pass below)
    f32x4 sq4v[4];
#pragma unroll
    for (int nt = 0; nt < 4; ++nt)
      sq4v[nt] = *(const f32x4*)(sqb + s0 + scol + nt * 16 + quad * 4);

    // GEMM1 (swapped): A = Xs-frag (m=s), B = Q-frag (n=t)
    // -> pacc[mt][nt][reg] = inner[t=trow+mt*16+l15][s=scol+nt*16+quad*4+reg]
    f32x4 pacc[2][4];
#pragma unroll
    for (int mt = 0; mt < 2; ++mt)
#pragma unroll
      for (int nt = 0; nt < 4; ++nt)
#pragma unroll
        for (int r = 0; r < 4; ++r) pacc[mt][nt][r] = 0.f;
#pragma unroll
    for (int nt = 0; nt < 4; ++nt) {
      const int srow = scol + nt * 16 + l15;
#pragma unroll
      for (int kk = 0; kk < 2; ++kk) {
        bf16x8v xfr = *(const bf16x8v*)&sm_xs[XS_IDX(srow, kk * 4 + quad)];
        pacc[0][nt] = __builtin_amdgcn_mfma_f32_16x16x32_bf16(xfr, qf[0][kk], pacc[0][nt], 0, 0, 0);
        pacc[1][nt] = __builtin_amdgcn_mfma_f32_16x16x32_bf16(xfr, qf[1][kk], pacc[1][nt], 0, 0, 0);
      }
    }

    // exp pass: lane-local s pairs -> cvt_pk -> ONE b64 P write per (nt,mt)
    // (8B-aligned by construction: row*280 % 8 == 0, col*2 % 8 == 0)
#pragma unroll
    for (int nt = 0; nt < 4; ++nt) {
      float cs0 = c1 * sq4v[nt][0], cs1 = c1 * sq4v[nt][1];
      float cs2 = c1 * sq4v[nt][2], cs3 = c1 * sq4v[nt][3];
#pragma unroll
      for (int mt = 0; mt < 2; ++mt) {
        unsigned short* prow = sm_p + (trow + mt * 16 + l15) * PSP + scol + nt * 16 + quad * 4;
        float g0 = c2 * pacc[mt][nt][0] - (sTrL[mt] + cs0);
        float g1 = c2 * pacc[mt][nt][1] - (sTrL[mt] + cs1);
        float g2 = c2 * pacc[mt][nt][2] - (sTrL[mt] + cs2);
        float g3 = c2 * pacc[mt][nt][3] - (sTrL[mt] + cs3);
        g0 = (g0 < 0.f) ? g0 : 0.f;
        g1 = (g1 < 0.f) ? g1 : 0.f;
        g2 = (g2 < 0.f) ? g2 : 0.f;
        g3 = (g3 < 0.f) ? g3 : 0.f;
        uint2 pk;
        pk.x = cvt_pk_bf16(EXP2F(g0), EXP2F(g1));
        pk.y = cvt_pk_bf16(EXP2F(g2), EXP2F(g3));
        *(uint2*)prow = pk;
      }
    }
    // no __syncthreads: each wave reads back only its own rows x col-half

    // GEMM2: O += P * Xs; A from sm_p (R7 layout), B from xst LDS (swizzled)
#pragma unroll
    for (int kk = 0; kk < 2; ++kk) {
      bf16x8v af[2];
#pragma unroll
      for (int mt = 0; mt < 2; ++mt)
        af[mt] = *(const bf16x8v*)(sm_p + (trow + mt * 16 + l15) * PSP + scol + kk * 32 + quad * 8);
#pragma unroll
      for (int nt = 0; nt < 4; ++nt) {
        bf16x8v bfr = *(const bf16x8v*)&sm_xst[XT_IDX(nt * 16 + l15, sch + kk * 4 + quad)];
        oacc[0][nt] = __builtin_amdgcn_mfma_f32_16x16x32_bf16(af[0], bfr, oacc[0][nt], 0, 0, 0);
        oacc[1][nt] = __builtin_amdgcn_mfma_f32_16x16x32_bf16(af[1], bfr, oacc[1][nt], 0, 0, 0);
      }
    }

    // pin next-tile loads live here (prevents sinking past the barrier)
    asm volatile("" :: "v"(a0.x), "v"(a0.y), "v"(a0.z), "v"(a0.w),
                       "v"(a1.x), "v"(a1.y), "v"(a1.z), "v"(a1.w),
                       "v"(b0.x), "v"(b0.y), "v"(b0.z), "v"(b0.w),
                       "v"(b1.x), "v"(b1.y), "v"(b1.z), "v"(b1.w));
    __syncthreads();
  }

  // combine the two S-half partial accumulators (waves w and w+4), then epilogue
  // (R7 proven: stride 33, 256x33x4 = 33792 B <= 35840 B sm_p)
  __syncthreads();
  float* scr = (float*)sm_p;
  if (sw == 1) {
#pragma unroll
    for (int mt = 0; mt < 2; ++mt)
#pragma unroll
      for (int nt = 0; nt < 4; ++nt)
#pragma unroll
        for (int reg = 0; reg < 4; ++reg)
          scr[(wq * 64 + lane) * 33 + (mt * 4 + nt) * 4 + reg] = oacc[mt][nt][reg];
  }
  __syncthreads();
  if (sw == 0) {
#pragma unroll
    for (int mt = 0; mt < 2; ++mt) {
#pragma unroll
      for (int nt = 0; nt < 4; ++nt) {
#pragma unroll
        for (int reg = 0; reg < 4; ++reg) {
          int row = trow + mt * 16 + quad * 4 + reg;
          int col = nt * 16 + l15;
          size_t idx = (size_t)((size_t)b * T_DIM + t0 + row) * C_DIM + col;
          float part = scr[(wq * 64 + lane) * 33 + (mt * 4 + nt) * 4 + reg];
          out[idx] = x[idx] + oacc[mt][nt][reg] + part;
        }
      }
    }
  }
}

// ---------------- fallback: proven r11 kernel (ws too small) ----------------
__global__ __launch_bounds__(256, 2)
void gauss_attn_f32(const float* __restrict__ x, const float* __restrict__ rs,
                    float* __restrict__ out) {
  __shared__ __align__(16) unsigned short sm_xst[C_DIM * PS];
  __shared__ __align__(16) unsigned short sm_p[BT * PS];
  __shared__ float sm_sT[BT];
  __shared__ float sm_sS[BS];
  __shared__ float sm_part[2 * BS];

  const int b = blockIdx.y, t0 = blockIdx.x * BT, tid = threadIdx.x;
  const int w = tid >> 6, lane = tid & 63, l15 = lane & 15, quad = lane >> 4;

  float sigma = rs[0];
  if (!(sigma == sigma) || !(sigma >= 0.f) || sigma > 1e3f) sigma = 0.01f;
  const float c1 = sigma * 1.4426950408889634f, c2 = 2.0f * c1;
  const float* xb = x + (size_t)b * T_DIM * C_DIM;

  if (tid < BT) {
    const f32x4* r4 = (const f32x4*)(xb + (size_t)(t0 + tid) * C_DIM);
    float s = 0.f;
#pragma unroll
    for (int i = 0; i < 16; ++i) { f32x4 v = r4[i]; s += v[0]*v[0] + v[1]*v[1] + v[2]*v[2] + v[3]*v[3]; }
    sm_sT[tid] = s;
  }
  bf16x8v qf[2][2];
#pragma unroll
  for (int mt = 0; mt < 2; ++mt) {
    const float* qp = xb + (size_t)(t0 + w * 32 + mt * 16 + l15) * C_DIM + quad * 8;
#pragma unroll
    for (int kk = 0; kk < 2; ++kk) {
      f32x4 a0 = *(const f32x4*)(qp + kk * 32);
      f32x4 a1 = *(const f32x4*)(qp + kk * 32 + 4);
      union { unsigned short u[8]; bf16x8v v; } pk;
#pragma unroll
      for (int j = 0; j < 4; ++j) { pk.u[j] = f32_to_bf16_rne(a0[j]); pk.u[4+j] = f32_to_bf16_rne(a1[j]); }
      qf[mt][kk] = pk.v;
    }
  }
  __syncthreads();
  float sTr[2][4];
#pragma unroll
  for (int mt = 0; mt < 2; ++mt)
#pragma unroll
    for (int reg = 0; reg < 4; ++reg) sTr[mt][reg] = c1 * sm_sT[w * 32 + mt * 16 + quad * 4 + reg];
  f32x4 oacc[2][4];
#pragma unroll
  for (int mt = 0; mt < 2; ++mt)
#pragma unroll
    for (int nt = 0; nt < 4; ++nt)
#pragma unroll
      for (int r = 0; r < 4; ++r) oacc[mt][nt][r] = 0.f;
  const int sidx = tid & 127, h = tid >> 7;
  for (int it = 0; it < T_DIM / BS; ++it) {
    const int s0 = it * BS;
    __syncthreads();
    {
      float part = 0.f;
      const float* sp = xb + (size_t)(s0 + sidx) * C_DIM + h * 32;
#pragma unroll
      for (int r = 0; r < 8; ++r) {
        f32x4 v = *(const f32x4*)(sp + r * 4);
        part += v[0]*v[0] + v[1]*v[1] + v[2]*v[2] + v[3]*v[3];
        const int c0 = h * 32 + r * 4;
        sm_xst[(c0+0)*PS+sidx] = f32_to_bf16_rne(v[0]);
        sm_xst[(c0+1)*PS+sidx] = f32_to_bf16_rne(v[1]);
        sm_xst[(c0+2)*PS+sidx] = f32_to_bf16_rne(v[2]);
        sm_xst[(c0+3)*PS+sidx] = f32_to_bf16_rne(v[3]);
      }
      sm_part[h * BS + sidx] = part;
    }
    __syncthreads();
    if (tid < BS) sm_sS[tid] = sm_part[tid] + sm_part[BS + tid];
    __syncthreads();
    f32x4 pacc[2][8];
#pragma unroll
    for (int mt = 0; mt < 2; ++mt)
#pragma unroll
      for (int nt = 0; nt < 8; ++nt)
#pragma unroll
        for (int r = 0; r < 4; ++r) pacc[mt][nt][r] = 0.f;
#pragma unroll
    for (int nt = 0; nt < 8; ++nt) {
      const float* bp = xb + (size_t)(s0 + nt * 16 + l15) * C_DIM + quad * 8;
#pragma unroll
      for (int kk = 0; kk < 2; ++kk) {
        f32x4 b0 = *(const f32x4*)(bp + kk * 32);
        f32x4 b1 = *(const f32x4*)(bp + kk * 32 + 4);
        union { unsigned short u[8]; bf16x8v v; } pk;
#pragma unroll
        for (int j = 0; j < 4; ++j) { pk.u[j] = f32_to_bf16_rne(b0[j]); pk.u[4+j] = f32_to_bf16_rne(b1[j]); }
        pacc[0][nt] = __builtin_amdgcn_mfma_f32_16x16x32_bf16(qf[0][kk], pk.v, pacc[0][nt], 0, 0, 0);
        pacc[1][nt] = __builtin_amdgcn_mfma_f32_16x16x32_bf16(qf[1][kk], pk.v, pacc[1][nt], 0, 0, 0);
      }
    }
#pragma unroll
    for (int nt = 0; nt < 8; ++nt) {
      const float sSv = c1 * sm_sS[nt * 16 + l15];
#pragma unroll
      for (int mt = 0; mt < 2; ++mt)
#pragma unroll
        for (int reg = 0; reg < 4; ++reg) {
          float arg = c2 * pacc[mt][nt][reg] - (sTr[mt][reg] + sSv);
          arg = (arg < 0.f) ? arg : 0.f;
          sm_p[(w*32+mt*16+quad*4+reg)*PS + nt*16+l15] = f32_to_bf16_rne(EXP2F(arg));
        }
    }
    __syncthreads();
#pragma unroll
    for (int kk = 0; kk < 4; ++kk) {
      bf16x8v af[2];
#pragma unroll
      for (int mt = 0; mt < 2; ++mt)
        af[mt] = *(const bf16x8v*)(sm_p + (w*32+mt*16+l15)*PS + kk*32 + quad*8);
#pragma unroll
      for (int nt = 0; nt < 4; ++nt) {
        bf16x8v bfr = *(const bf16x8v*)(sm_xst + (nt*16+l15)*PS + kk*32 + quad*8);
        oacc[0][nt] = __builtin_amdgcn_mfma_f32_16x16x32_bf16(af[0], bfr, oacc[0][nt], 0, 0, 0);
        oacc[1][nt] = __builtin_amdgcn_mfma_f32_16x16x32_bf16(af[1], bfr, oacc[1][nt], 0, 0, 0);
      }
    }
  }
#pragma unroll
  for (int mt = 0; mt < 2; ++mt)
#pragma unroll
    for (int nt = 0; nt < 4; ++nt)
#pragma unroll
      for (int reg = 0; reg < 4; ++reg) {
        int row = w * 32 + mt * 16 + quad * 4 + reg;
        int col = nt * 16 + l15;
        size_t idx = (size_t)((size_t)b * T_DIM + t0 + row) * C_DIM + col;
        out[idx] = x[idx] + oacc[mt][nt][reg];
      }
}

extern "C" void kernel_launch(void* const* d_in, const int* in_sizes, int n_in,
                              void* d_out, int out_size, void* d_ws, size_t ws_size,
                              hipStream_t stream) {
  const float* x  = (const float*)d_in[0];
  const float* rs = (const float*)d_in[1];
  float* outp = (float*)d_out;
  int B = in_sizes[0] / (T_DIM * C_DIM);
  if (B < 1) B = 1;
  size_t xel = (size_t)B * T_DIM * C_DIM;
  size_t need = xel * 2 * 2 + (size_t)B * T_DIM * 4;
  if (ws_size >= need) {
    unsigned short* xbf  = (unsigned short*)d_ws;
    unsigned short* xtbf = xbf + xel;
    float* sq = (float*)(xtbf + xel);
    pre_cast<<<dim3(T_DIM / 64, B), 256, 0, stream>>>(x, xbf, xtbf, sq);
    gauss_main<<<dim3(T_DIM / BT, B), 512, 0, stream>>>(x, xbf, xtbf, sq, rs, outp);
  } else {
    gauss_attn_f32<<<dim3(T_DIM / BT, B), 256, 0, stream>>>(x, rs, outp);
  }
}